// Round 5
// baseline (3461.256 us; speedup 1.0000x reference)
//
#include <hip/hip_runtime.h>
#include <hip/hip_fp16.h>
#include <math.h>

// MSMOM: multi-scale soft morphological opening + BN/ReLU + 1x1 conv + BN/ReLU
// B=4, C=64, H=W=256, k=3, dilations 1..4, beta=15.
//
// Morph computed in exp2-domain: soft-ero/dil are linear correlations on
// P = 2^{-K x} (K = beta*log2e).  S1 = sum W*P  ->  2^{K e} = 1/S1 (rcp);
// dilation: out = C1*log2( sum Wd * (1/S1) ).  No per-pixel max needed:
// 2^{-Kx} spans 2^+-119 (x ~ N(0,1)) and 2^{Ke} spans ~2^[-108,43], both
// within fp32.  Flush-to-zero corner cases land on relu-0-correct outputs.

constexpr int C_ = 64, H_ = 256, W_ = 256;
constexpr int HW = H_ * W_;
constexpr float EPSV = 1e-5f;
constexpr float KL2E = 21.64042561333445f;    // beta * log2(e)
constexpr float C1   = 0.046209812037329684f; // ln(2) / beta

typedef __attribute__((ext_vector_type(8))) _Float16 half8v;
typedef __attribute__((ext_vector_type(4))) _Float16 half4v;
typedef __attribute__((ext_vector_type(4))) float f32x4;
typedef __attribute__((ext_vector_type(2))) float f32x2;

__device__ _Float16 g_wh[64 * 256];  // conv weights fp16, row-major [o][c]
__device__ float g_scale[64];
__device__ float g_shift[64];
__device__ float g_we9e[4 * 64 * 9]; // 2^{K*we}  (morph erosion weights, exp2-domain)
__device__ float g_wd9e[4 * 64 * 9]; // 2^{K*wd}  (morph dilation weights, exp2-domain)
__device__ float g_cs[4 * 64];       // C1 * bn_scale  (per d,c)
__device__ float g_sh[4 * 64];       // bn shift       (per d,c)

__global__ __launch_bounds__(256) void prep(
    const float* __restrict__ cw, const float* __restrict__ g,
    const float* __restrict__ bb, const float* __restrict__ bm,
    const float* __restrict__ bv, const float* __restrict__ we,
    const float* __restrict__ wd, const float* __restrict__ bng,
    const float* __restrict__ bnb, const float* __restrict__ bnm,
    const float* __restrict__ bnv)
{
    int i = blockIdx.x * 256 + threadIdx.x;  // 16384 total
    g_wh[i] = (_Float16)cw[i];
    if (i < 64) {
        float s = g[i] * rsqrtf(bv[i] + EPSV);
        g_scale[i] = s;
        g_shift[i] = bb[i] - bm[i] * s;
    }
    if (i < 2304) {  // 4*64*9 morph weights, exp2-domain (hoisted out of morph_all)
        g_we9e[i] = __builtin_amdgcn_exp2f(KL2E * we[i]);
        g_wd9e[i] = __builtin_amdgcn_exp2f(KL2E * wd[i]);
    }
    if (i < 256) {   // per-(d,c) BN constants
        float s = bng[i] * rsqrtf(bnv[i] + EPSV);
        g_cs[i] = C1 * s;
        g_sh[i] = bnb[i] - bnm[i] * s;
    }
}

// One block = one 64x64 tile of one (b,c); all 4 dilations reuse staged P.
// xs: P = 2^{-K x}, 80 rows x 80 cols, stride 92 (28 mod 32 -> row bank
// offsets cycle uniformly over all 8 cosets).  es: 2^{K e}, 72 rows x 72
// cols, stride 76 (12 mod 32).  Layout identical to the proven round-1
// version; this round only packs the tap FMAs as f32x2 (v_pk_fma_f32):
// pairs (2t, 2t+1) with even tap base share an aligned VGPR pair -> one
// packed FMA, identical IEEE math.  Even base: all j for D=2,4; j=1 for
// D=1,3.  ~33% fewer FMA instructions in the hot loops.
__global__ __launch_bounds__(256) void morph_all(
    const float* __restrict__ x, _Float16* __restrict__ cat)
{
    __shared__ __align__(16) float xs[80 * 92];
    __shared__ __align__(16) float es[72 * 76];
    const int tid = threadIdx.x;
    const int tileW = blockIdx.x & 3, tileH = blockIdx.x >> 2;  // 4x4 tiles
    const int c = blockIdx.y, b = blockIdx.z;
    const int h0 = tileH * 64, w0 = tileW * 64;
    const float* xc = x + (b * C_ + c) * HW;

    // staging: P = 2^{-K x}; out-of-image -> 0 (== 2^{-K*BIG} exactly).
    for (int u = tid; u < 1600; u += 256) {
        int r = u / 20, q4 = (u - r * 20) * 4;
        int gh = h0 - 8 + r, gw = w0 - 8 + q4;
        int ch = min(max(gh, 0), 255), cwi = min(max(gw, 0), 252);
        const float4 v = *(const float4*)&xc[ch * W_ + cwi];
        bool ok = ((unsigned)gh < 256u) && ((unsigned)gw < 253u);
        float4 sv;
        sv.x = ok ? __builtin_amdgcn_exp2f(-KL2E * v.x) : 0.f;
        sv.y = ok ? __builtin_amdgcn_exp2f(-KL2E * v.y) : 0.f;
        sv.z = ok ? __builtin_amdgcn_exp2f(-KL2E * v.z) : 0.f;
        sv.w = ok ? __builtin_amdgcn_exp2f(-KL2E * v.w) : 0.f;
        *(float4*)&xs[r * 92 + q4] = sv;
    }

    #pragma unroll
    for (int d = 0; d < 4; d++) {
        const int D = d + 1;
        const int bc = d * C_ + c;

        float w9[9], wd9[9];
        #pragma unroll
        for (int i = 0; i < 9; i++) {
            w9[i]  = g_we9e[bc * 9 + i];
            wd9[i] = g_wd9e[bc * 9 + i];
        }
        const float cs = g_cs[bc];
        const float shift = g_sh[bc];

        __syncthreads();  // staging done / previous dilation reads of es done

        // erosion: 5 col-groups x 72 rows, column-major (bank-uniform).
        for (int g = tid; g < 360; g += 256) {
            const int col = g / 72;
            const int row = g - col * 72;
            const int qa0 = col * 16;
            f32x2 s2[8];
            #pragma unroll
            for (int t = 0; t < 8; t++) s2[t] = (f32x2){0.f, 0.f};
            #pragma unroll
            for (int i = 0; i < 3; i++) {
                const f32x4* xr = (const f32x4*)&xs[(row + 4 + (i - 1) * D) * 92 + qa0];
                f32x4 xw[6];
                #pragma unroll
                for (int k = 0; k < 6; k++) xw[k] = xr[k];
                #pragma unroll
                for (int j = 0; j < 3; j++) {
                    const float wv = w9[i * 3 + j];
                    const int bs = (4 - D) + j * D;   // compile-time
                    if ((bs & 1) == 0) {
                        const f32x2 wv2 = {wv, wv};
                        #pragma unroll
                        for (int t = 0; t < 8; t++) {
                            const int wi = bs + 2 * t;
                            f32x2 xp = {xw[wi >> 2][wi & 3], xw[(wi + 1) >> 2][(wi + 1) & 3]};
                            s2[t] = __builtin_elementwise_fma(wv2, xp, s2[t]);
                        }
                    } else {
                        #pragma unroll
                        for (int t = 0; t < 8; t++) {
                            const int wi = bs + 2 * t;
                            s2[t].x = fmaf(wv, xw[wi >> 2][wi & 3], s2[t].x);
                            s2[t].y = fmaf(wv, xw[(wi + 1) >> 2][(wi + 1) & 3], s2[t].y);
                        }
                    }
                }
            }
            const bool rowok = (unsigned)(h0 + row - 4) < 256u;
            const int gw0 = w0 + qa0 - 4;
            f32x4 ev[4];
            #pragma unroll
            for (int p = 0; p < 16; p++) {
                float sval = (p & 1) ? s2[p >> 1].y : s2[p >> 1].x;
                float gv = __builtin_amdgcn_rcpf(fmaxf(sval, 1e-38f));
                bool ok = rowok && ((unsigned)(gw0 + p) < 256u);
                ev[p >> 2][p & 3] = ok ? gv : 0.f;  // pad: 2^{K*(-BIG)} = 0
            }
            f32x4* ep = (f32x4*)&es[row * 76 + qa0];
            ep[0] = ev[0]; ep[1] = ev[1];
            if (qa0 < 64) { ep[2] = ev[2]; ep[3] = ev[3]; }  // cols 72..79 never read
        }

        __syncthreads();  // es ready

        // dilation: 64 rows x 4 col-groups of 16 px, one group per thread
        {
            const int dr = tid >> 2, dq0 = (tid & 3) * 16;
            f32x2 s2[8];
            #pragma unroll
            for (int t = 0; t < 8; t++) s2[t] = (f32x2){0.f, 0.f};
            #pragma unroll
            for (int i = 0; i < 3; i++) {
                const f32x4* er = (const f32x4*)&es[(dr + 4 + (i - 1) * D) * 76 + dq0];
                f32x4 ew[6];
                #pragma unroll
                for (int k = 0; k < 6; k++) ew[k] = er[k];
                #pragma unroll
                for (int j = 0; j < 3; j++) {
                    const float wv = wd9[i * 3 + j];
                    const int bs = (4 - D) + j * D;
                    if ((bs & 1) == 0) {
                        const f32x2 wv2 = {wv, wv};
                        #pragma unroll
                        for (int t = 0; t < 8; t++) {
                            const int wi = bs + 2 * t;
                            f32x2 xp = {ew[wi >> 2][wi & 3], ew[(wi + 1) >> 2][(wi + 1) & 3]};
                            s2[t] = __builtin_elementwise_fma(wv2, xp, s2[t]);
                        }
                    } else {
                        #pragma unroll
                        for (int t = 0; t < 8; t++) {
                            const int wi = bs + 2 * t;
                            s2[t].x = fmaf(wv, ew[wi >> 2][wi & 3], s2[t].x);
                            s2[t].y = fmaf(wv, ew[(wi + 1) >> 2][(wi + 1) & 3], s2[t].y);
                        }
                    }
                }
            }
            half8v hv0, hv1;
            #pragma unroll
            for (int p = 0; p < 16; p++) {
                float sval = (p & 1) ? s2[p >> 1].y : s2[p >> 1].x;
                float y = __builtin_amdgcn_logf(fmaxf(sval, 1e-38f)) * cs + shift;
                y = fmaxf(0.f, y);
                if (p < 8) hv0[p] = (_Float16)y; else hv1[p - 8] = (_Float16)y;
            }
            _Float16* cp = &cat[((size_t)((b * 4 + d) * C_ + c)) * HW
                                + (h0 + dr) * W_ + (w0 + dq0)];
            *(half8v*)cp = hv0;
            *(half8v*)(cp + 8) = hv1;
        }
    }
}

// Out[64 x 65536] = W[64x256] * Cat[256x65536] per batch via mfma_f32_16x16x32_f16.
//
// BARRIER-FREE wave-private pipeline: each wave's B-fragment tr-reads touch
// only its own 5120-B region (trbase = wave*5120 + ...), so each wave stages
// its OWN 64-px strip (all 32 k-rows) -> producer == consumer, no
// __syncthreads, no compiler vmcnt(0) barrier drains.  Same LDS bytes at the
// same addresses as the proven round-4 layout (element (k,px) at halves
// (px>>4)*640 + (k>>2)*80 + (k&3)*16 + (px&15), buf*10240); only the writing
// lane mapping changed (row = lane>>1, half-strip = lane&1).
//
// VMEM FIFO discipline: A-loads (g_wh, L1-resident) are issued BEFORE the
// cat prefetch so the MFMA's implicit wait is vmcnt(4) -- it no longer
// drains the depth-2 HBM prefetch.  Write->tr-read ordering is fenced with
// an explicit lgkmcnt(0) + sched_barrier(0) (wave-local, cheap).
//
// ds_read_b64_tr_b16 (proven round 4): lane addr = sub_base + (lane&15)*8;
// the 16-lane group cooperatively reads the 128-B [4 kr][16 m] subtile and
// lane m receives column m (elem j = kr j).  k = quad*8 + h*4 + j.
__global__ __launch_bounds__(256) void conv_mfma(
    const _Float16* __restrict__ cat, float* __restrict__ out)
{
    __shared__ __align__(16) _Float16 T[2][10240];  // 40,960 B
    const int tid = threadIdx.x;
    const int lane = tid & 63, wave = tid >> 6;
    const int m = lane & 15, quad = lane >> 4;
    const int b = blockIdx.y;
    const int px0 = blockIdx.x * 256;
    const _Float16* catb = cat + (size_t)b * 256 * HW + px0;

    // wave-private staging: lane covers k-row cl2 = lane>>1, half-strip s
    const int cl2 = lane >> 1, s = lane & 1;
    const int pxw = wave * 64 + s * 8;               // global px base (+p*16)
    // LDS write offset (halves): wave region + [pt=p][c4][kr][m]
    const int wbase = wave * 2560 + (cl2 >> 2) * 80 + (cl2 & 3) * 16 + s * 8;

    const uint t0a = (uint)(uintptr_t)&T[0][0];      // LDS byte address
    const uint trbase = t0a + wave * 5120 + quad * 320 + m * 8;

    f32x4 acc[4][4];
    #pragma unroll
    for (int ot = 0; ot < 4; ot++)
        #pragma unroll
        for (int pt = 0; pt < 4; pt++)
            acc[ot][pt] = (f32x4){0.f, 0.f, 0.f, 0.f};

    half8v sv[2][4];
    #pragma unroll
    for (int p = 0; p < 4; p++) {
        sv[0][p] = *(const half8v*)&catb[(size_t)cl2 * HW + pxw + p * 16];
        sv[1][p] = *(const half8v*)&catb[(size_t)(32 + cl2) * HW + pxw + p * 16];
    }

    #pragma unroll
    for (int kc = 0; kc < 8; kc++) {
        const int buf = kc & 1;
        const int c0 = kc * 32;
        // stage chunk (loaded 2 iterations ago) into this wave's region
        _Float16* tw = &T[buf][0] + wbase;
        #pragma unroll
        for (int p = 0; p < 4; p++)
            *(half8v*)(tw + p * 640) = sv[buf][p];

        // A fragments first (L1), THEN the HBM prefetch: vmcnt FIFO keeps
        // the prefetch outstanding across the MFMA phase.
        half8v a0 = *(const half8v*)&g_wh[(0  + m) * 256 + c0 + quad * 8];
        half8v a1 = *(const half8v*)&g_wh[(16 + m) * 256 + c0 + quad * 8];
        half8v a2 = *(const half8v*)&g_wh[(32 + m) * 256 + c0 + quad * 8];
        half8v a3 = *(const half8v*)&g_wh[(48 + m) * 256 + c0 + quad * 8];

        if (kc < 6) {  // prefetch for kc+2
            #pragma unroll
            for (int p = 0; p < 4; p++)
                sv[buf][p] = *(const half8v*)&catb[(size_t)(c0 + 64 + cl2) * HW + pxw + p * 16];
        }

        // wave-local fence: staged writes complete before tr reads
        asm volatile("s_waitcnt lgkmcnt(0)");
        __builtin_amdgcn_sched_barrier(0);

        // B fragments: 2 tr reads per pt, lane addr covers the 128-B subtile
        const uint tb = trbase + buf * 20480;
        f32x2 trd[4][2];
        #pragma unroll
        for (int pt = 0; pt < 4; pt++) {
            asm volatile("ds_read_b64_tr_b16 %0, %1"
                         : "=v"(trd[pt][0]) : "v"(tb + pt * 1280));
            asm volatile("ds_read_b64_tr_b16 %0, %1"
                         : "=v"(trd[pt][1]) : "v"(tb + pt * 1280 + 160));
        }
        asm volatile("s_waitcnt lgkmcnt(0)");
        __builtin_amdgcn_sched_barrier(0);  // rule 18: keep MFMAs below the wait

        #pragma unroll
        for (int pt = 0; pt < 4; pt++) {
            half4v lo = __builtin_bit_cast(half4v, trd[pt][0]);
            half4v hi = __builtin_bit_cast(half4v, trd[pt][1]);
            half8v bf = __builtin_shufflevector(lo, hi, 0, 1, 2, 3, 4, 5, 6, 7);
            acc[0][pt] = __builtin_amdgcn_mfma_f32_16x16x32_f16(a0, bf, acc[0][pt], 0, 0, 0);
            acc[1][pt] = __builtin_amdgcn_mfma_f32_16x16x32_f16(a1, bf, acc[1][pt], 0, 0, 0);
            acc[2][pt] = __builtin_amdgcn_mfma_f32_16x16x32_f16(a2, bf, acc[2][pt], 0, 0, 0);
            acc[3][pt] = __builtin_amdgcn_mfma_f32_16x16x32_f16(a3, bf, acc[3][pt], 0, 0, 0);
        }
    }

    // D layout: row(o) = quad*4 + reg, col(px) = m
    #pragma unroll
    for (int ot = 0; ot < 4; ot++)
        #pragma unroll
        for (int reg = 0; reg < 4; reg++) {
            const int o = ot * 16 + quad * 4 + reg;
            const float sc = g_scale[o], sh = g_shift[o];
            float* ob = out + ((size_t)(b * 64 + o)) * HW + px0;
            #pragma unroll
            for (int pt = 0; pt < 4; pt++) {
                const int pxl = wave * 64 + pt * 16 + m;
                ob[pxl] = fmaxf(0.f, acc[ot][pt][reg] * sc + sh);
            }
        }
}

extern "C" void kernel_launch(void* const* d_in, const int* in_sizes, int n_in,
                              void* d_out, int out_size, void* d_ws, size_t ws_size,
                              hipStream_t stream)
{
    const float* x   = (const float*)d_in[0];
    const float* we  = (const float*)d_in[1];
    const float* wd  = (const float*)d_in[2];
    const float* bng = (const float*)d_in[3];
    const float* bnb = (const float*)d_in[4];
    const float* bnm = (const float*)d_in[5];
    const float* bnv = (const float*)d_in[6];
    const float* cw  = (const float*)d_in[7];
    const float* fg  = (const float*)d_in[8];
    const float* fb  = (const float*)d_in[9];
    const float* fm  = (const float*)d_in[10];
    const float* fv  = (const float*)d_in[11];
    float* out = (float*)d_out;
    _Float16* cat = (_Float16*)d_ws;  // 4*256*65536*2 B = 128 MiB

    prep<<<64, 256, 0, stream>>>(cw, fg, fb, fm, fv, we, wd, bng, bnb, bnm, bnv);
    morph_all<<<dim3(16, 64, 4), 256, 0, stream>>>(x, cat);
    conv_mfma<<<dim3(256, 4), 256, 0, stream>>>(cat, out);
}

// Round 6
// 248.701 us; speedup vs baseline: 13.9174x; 13.9174x over previous
//
#include <hip/hip_runtime.h>
#include <hip/hip_fp16.h>
#include <math.h>

// MSMOM: multi-scale soft morphological opening + BN/ReLU + 1x1 conv + BN/ReLU
// B=4, C=64, H=W=256, k=3, dilations 1..4, beta=15.
//
// Morph computed in exp2-domain: soft-ero/dil are linear correlations on
// P = 2^{-K x} (K = beta*log2e).  S1 = sum W*P  ->  2^{K e} = 1/S1 (rcp);
// dilation: out = C1*log2( sum Wd * (1/S1) ).  No per-pixel max needed:
// 2^{-Kx} spans 2^+-119 (x ~ N(0,1)) and 2^{Ke} spans ~2^[-108,43], both
// within fp32.  Flush-to-zero corner cases land on relu-0-correct outputs.
//
// History notes (keep): pk-FMA (f32x2 __builtin_elementwise_fma) in morph
// RETIRED — r5 showed VGPR 68->172, occupancy collapse, 30x regression
// (pair-alignment v_movs).  Scalar fmaf body below is the proven fast form.

constexpr int C_ = 64, H_ = 256, W_ = 256;
constexpr int HW = H_ * W_;
constexpr float EPSV = 1e-5f;
constexpr float KL2E = 21.64042561333445f;    // beta * log2(e)
constexpr float C1   = 0.046209812037329684f; // ln(2) / beta

typedef __attribute__((ext_vector_type(8))) _Float16 half8v;
typedef __attribute__((ext_vector_type(4))) _Float16 half4v;
typedef __attribute__((ext_vector_type(4))) float f32x4;
typedef __attribute__((ext_vector_type(2))) float f32x2;

__device__ _Float16 g_wh[64 * 256];  // conv weights fp16, row-major [o][c]
__device__ float g_scale[64];
__device__ float g_shift[64];
__device__ float g_we9e[4 * 64 * 9]; // 2^{K*we}  (morph erosion weights, exp2-domain)
__device__ float g_wd9e[4 * 64 * 9]; // 2^{K*wd}  (morph dilation weights, exp2-domain)
__device__ float g_cs[4 * 64];       // C1 * bn_scale  (per d,c)
__device__ float g_sh[4 * 64];       // bn shift       (per d,c)

__global__ __launch_bounds__(256) void prep(
    const float* __restrict__ cw, const float* __restrict__ g,
    const float* __restrict__ bb, const float* __restrict__ bm,
    const float* __restrict__ bv, const float* __restrict__ we,
    const float* __restrict__ wd, const float* __restrict__ bng,
    const float* __restrict__ bnb, const float* __restrict__ bnm,
    const float* __restrict__ bnv)
{
    int i = blockIdx.x * 256 + threadIdx.x;  // 16384 total
    g_wh[i] = (_Float16)cw[i];
    if (i < 64) {
        float s = g[i] * rsqrtf(bv[i] + EPSV);
        g_scale[i] = s;
        g_shift[i] = bb[i] - bm[i] * s;
    }
    if (i < 2304) {  // 4*64*9 morph weights, exp2-domain (hoisted out of morph_all)
        g_we9e[i] = __builtin_amdgcn_exp2f(KL2E * we[i]);
        g_wd9e[i] = __builtin_amdgcn_exp2f(KL2E * wd[i]);
    }
    if (i < 256) {   // per-(d,c) BN constants
        float s = bng[i] * rsqrtf(bnv[i] + EPSV);
        g_cs[i] = C1 * s;
        g_sh[i] = bnb[i] - bnm[i] * s;
    }
}

// One block = one 64x64 tile of one (b,c); all 4 dilations reuse staged P.
// xs: P = 2^{-K x}, 80 rows x 80 cols, stride 92 (28 mod 32 -> row bank
// offsets cycle uniformly over all 8 cosets).  es: 2^{K e}, 72 rows x 72
// cols, stride 76 (12 mod 32 -> also all 8 cosets; dilation never reads
// cols >71, and the erosion's last col-group writes only cols 64..71).
// PROVEN round-1 body (113 us, VGPR 68) — do not touch the FMA form.
__global__ __launch_bounds__(256) void morph_all(
    const float* __restrict__ x, _Float16* __restrict__ cat)
{
    __shared__ __align__(16) float xs[80 * 92];
    __shared__ __align__(16) float es[72 * 76];
    const int tid = threadIdx.x;
    const int tileW = blockIdx.x & 3, tileH = blockIdx.x >> 2;  // 4x4 tiles
    const int c = blockIdx.y, b = blockIdx.z;
    const int h0 = tileH * 64, w0 = tileW * 64;
    const float* xc = x + (b * C_ + c) * HW;

    // staging: P = 2^{-K x}; out-of-image -> 0 (== 2^{-K*BIG} exactly).
    // 80 rows x 20 float4-groups; group col-validity is all-or-nothing.
    for (int u = tid; u < 1600; u += 256) {
        int r = u / 20, q4 = (u - r * 20) * 4;
        int gh = h0 - 8 + r, gw = w0 - 8 + q4;
        int ch = min(max(gh, 0), 255), cwi = min(max(gw, 0), 252);
        const float4 v = *(const float4*)&xc[ch * W_ + cwi];
        bool ok = ((unsigned)gh < 256u) && ((unsigned)gw < 253u);
        float4 sv;
        sv.x = ok ? __builtin_amdgcn_exp2f(-KL2E * v.x) : 0.f;
        sv.y = ok ? __builtin_amdgcn_exp2f(-KL2E * v.y) : 0.f;
        sv.z = ok ? __builtin_amdgcn_exp2f(-KL2E * v.z) : 0.f;
        sv.w = ok ? __builtin_amdgcn_exp2f(-KL2E * v.w) : 0.f;
        *(float4*)&xs[r * 92 + q4] = sv;
    }

    #pragma unroll
    for (int d = 0; d < 4; d++) {
        const int D = d + 1;
        const int bc = d * C_ + c;

        // weights + BN constants: precomputed in prep, wave-uniform loads
        float w9[9], wd9[9];
        #pragma unroll
        for (int i = 0; i < 9; i++) {
            w9[i]  = g_we9e[bc * 9 + i];
            wd9[i] = g_wd9e[bc * 9 + i];
        }
        const float cs = g_cs[bc];
        const float shift = g_sh[bc];

        __syncthreads();  // staging done / previous dilation reads of es done

        // erosion: 5 col-groups x 72 rows, column-major (bank-uniform).
        // es row a <-> image row h0-4+a <-> xs row a+4.
        for (int g = tid; g < 360; g += 256) {
            const int col = g / 72;            // wave-uniform-ish
            const int row = g - col * 72;
            const int qa0 = col * 16;
            float s16[16];
            #pragma unroll
            for (int p = 0; p < 16; p++) s16[p] = 0.f;
            #pragma unroll
            for (int i = 0; i < 3; i++) {
                const f32x4* xr = (const f32x4*)&xs[(row + 4 + (i - 1) * D) * 92 + qa0];
                f32x4 xw[6];
                #pragma unroll
                for (int k = 0; k < 6; k++) xw[k] = xr[k];
                #pragma unroll
                for (int j = 0; j < 3; j++) {
                    const float wv = w9[i * 3 + j];
                    #pragma unroll
                    for (int p = 0; p < 16; p++) {
                        const int wi = (4 - D) + p + j * D;  // compile-time
                        s16[p] = fmaf(wv, xw[wi >> 2][wi & 3], s16[p]);
                    }
                }
            }
            const bool rowok = (unsigned)(h0 + row - 4) < 256u;
            const int gw0 = w0 + qa0 - 4;
            f32x4 ev[4];
            #pragma unroll
            for (int p = 0; p < 16; p++) {
                float gv = __builtin_amdgcn_rcpf(fmaxf(s16[p], 1e-38f));
                bool ok = rowok && ((unsigned)(gw0 + p) < 256u);
                ev[p >> 2][p & 3] = ok ? gv : 0.f;  // pad: 2^{K*(-BIG)} = 0
            }
            f32x4* ep = (f32x4*)&es[row * 76 + qa0];
            ep[0] = ev[0]; ep[1] = ev[1];
            if (qa0 < 64) { ep[2] = ev[2]; ep[3] = ev[3]; }  // cols 72..79 never read
        }

        __syncthreads();  // es ready

        // dilation: 64 rows x 4 col-groups of 16 px, one group per thread
        {
            const int dr = tid >> 2, dq0 = (tid & 3) * 16;
            float s16[16];
            #pragma unroll
            for (int p = 0; p < 16; p++) s16[p] = 0.f;
            #pragma unroll
            for (int i = 0; i < 3; i++) {
                const f32x4* er = (const f32x4*)&es[(dr + 4 + (i - 1) * D) * 76 + dq0];
                f32x4 ew[6];
                #pragma unroll
                for (int k = 0; k < 6; k++) ew[k] = er[k];
                #pragma unroll
                for (int j = 0; j < 3; j++) {
                    const float wv = wd9[i * 3 + j];
                    #pragma unroll
                    for (int p = 0; p < 16; p++) {
                        const int wi = (4 - D) + p + j * D;
                        s16[p] = fmaf(wv, ew[wi >> 2][wi & 3], s16[p]);
                    }
                }
            }
            half8v hv0, hv1;
            #pragma unroll
            for (int p = 0; p < 16; p++) {
                float y = __builtin_amdgcn_logf(fmaxf(s16[p], 1e-38f)) * cs + shift;
                y = fmaxf(0.f, y);
                if (p < 8) hv0[p] = (_Float16)y; else hv1[p - 8] = (_Float16)y;
            }
            _Float16* cp = &cat[((size_t)((b * 4 + d) * C_ + c)) * HW
                                + (h0 + dr) * W_ + (w0 + dq0)];
            *(half8v*)cp = hv0;
            *(half8v*)(cp + 8) = hv1;
        }
    }
}

// Out[64 x 65536] = W[64x256] * Cat[256x65536] per batch via mfma_f32_16x16x32_f16.
//
// BARRIER-FREE wave-private pipeline (proven r5): each wave's B-fragment
// tr-reads touch only its own 5120-B region, so each wave stages its OWN
// 64-px strip (all 32 k-rows) -> producer == consumer, no __syncthreads,
// no compiler vmcnt(0) barrier drains.  Same LDS bytes/addresses as the
// proven r4 layout; only the writing lane mapping differs
// (row = lane>>1, half-strip = lane&1).
//
// VMEM FIFO discipline: A-loads (g_wh, L1-resident) are issued BEFORE the
// cat prefetch so the MFMA's implicit wait is vmcnt(4) -- it no longer
// drains the depth-2 HBM prefetch.  Write->tr-read ordering fenced with
// lgkmcnt(0) (+"memory" clobber so ds_writes can't sink past it) +
// sched_barrier(0).
//
// ds_read_b64_tr_b16 (proven r4): lane addr = sub_base + (lane&15)*8;
// the 16-lane group cooperatively reads the 128-B [4 kr][16 m] subtile and
// lane m receives column m (elem j = kr j).  k = quad*8 + h*4 + j.
__global__ __launch_bounds__(256) void conv_mfma(
    const _Float16* __restrict__ cat, float* __restrict__ out)
{
    __shared__ __align__(16) _Float16 T[2][10240];  // 40,960 B
    const int tid = threadIdx.x;
    const int lane = tid & 63, wave = tid >> 6;
    const int m = lane & 15, quad = lane >> 4;
    const int b = blockIdx.y;
    const int px0 = blockIdx.x * 256;
    const _Float16* catb = cat + (size_t)b * 256 * HW + px0;

    // wave-private staging: lane covers k-row cl2 = lane>>1, half-strip s
    const int cl2 = lane >> 1, s = lane & 1;
    const int pxw = wave * 64 + s * 8;               // global px base (+p*16)
    // LDS write offset (halves): wave region + [pt=p][c4][kr][m]
    const int wbase = wave * 2560 + (cl2 >> 2) * 80 + (cl2 & 3) * 16 + s * 8;

    const uint t0a = (uint)(uintptr_t)&T[0][0];      // LDS byte address
    const uint trbase = t0a + wave * 5120 + quad * 320 + m * 8;

    f32x4 acc[4][4];
    #pragma unroll
    for (int ot = 0; ot < 4; ot++)
        #pragma unroll
        for (int pt = 0; pt < 4; pt++)
            acc[ot][pt] = (f32x4){0.f, 0.f, 0.f, 0.f};

    half8v sv[2][4];
    #pragma unroll
    for (int p = 0; p < 4; p++) {
        sv[0][p] = *(const half8v*)&catb[(size_t)cl2 * HW + pxw + p * 16];
        sv[1][p] = *(const half8v*)&catb[(size_t)(32 + cl2) * HW + pxw + p * 16];
    }

    #pragma unroll
    for (int kc = 0; kc < 8; kc++) {
        const int buf = kc & 1;
        const int c0 = kc * 32;
        // stage chunk (loaded 2 iterations ago) into this wave's region
        _Float16* tw = &T[buf][0] + wbase;
        #pragma unroll
        for (int p = 0; p < 4; p++)
            *(half8v*)(tw + p * 640) = sv[buf][p];

        // A fragments first (L1), THEN the HBM prefetch: vmcnt FIFO keeps
        // the prefetch outstanding across the MFMA phase.
        half8v a0 = *(const half8v*)&g_wh[(0  + m) * 256 + c0 + quad * 8];
        half8v a1 = *(const half8v*)&g_wh[(16 + m) * 256 + c0 + quad * 8];
        half8v a2 = *(const half8v*)&g_wh[(32 + m) * 256 + c0 + quad * 8];
        half8v a3 = *(const half8v*)&g_wh[(48 + m) * 256 + c0 + quad * 8];

        if (kc < 6) {  // prefetch for kc+2
            #pragma unroll
            for (int p = 0; p < 4; p++)
                sv[buf][p] = *(const half8v*)&catb[(size_t)(c0 + 64 + cl2) * HW + pxw + p * 16];
        }

        // wave-local fence: staged writes complete before tr reads
        asm volatile("s_waitcnt lgkmcnt(0)" ::: "memory");
        __builtin_amdgcn_sched_barrier(0);

        // B fragments: 2 tr reads per pt, lane addr covers the 128-B subtile
        const uint tb = trbase + buf * 20480;
        f32x2 trd[4][2];
        #pragma unroll
        for (int pt = 0; pt < 4; pt++) {
            asm volatile("ds_read_b64_tr_b16 %0, %1"
                         : "=v"(trd[pt][0]) : "v"(tb + pt * 1280));
            asm volatile("ds_read_b64_tr_b16 %0, %1"
                         : "=v"(trd[pt][1]) : "v"(tb + pt * 1280 + 160));
        }
        asm volatile("s_waitcnt lgkmcnt(0)");
        __builtin_amdgcn_sched_barrier(0);  // rule 18: keep MFMAs below the wait

        #pragma unroll
        for (int pt = 0; pt < 4; pt++) {
            half4v lo = __builtin_bit_cast(half4v, trd[pt][0]);
            half4v hi = __builtin_bit_cast(half4v, trd[pt][1]);
            half8v bf = __builtin_shufflevector(lo, hi, 0, 1, 2, 3, 4, 5, 6, 7);
            acc[0][pt] = __builtin_amdgcn_mfma_f32_16x16x32_f16(a0, bf, acc[0][pt], 0, 0, 0);
            acc[1][pt] = __builtin_amdgcn_mfma_f32_16x16x32_f16(a1, bf, acc[1][pt], 0, 0, 0);
            acc[2][pt] = __builtin_amdgcn_mfma_f32_16x16x32_f16(a2, bf, acc[2][pt], 0, 0, 0);
            acc[3][pt] = __builtin_amdgcn_mfma_f32_16x16x32_f16(a3, bf, acc[3][pt], 0, 0, 0);
        }
    }

    // D layout: row(o) = quad*4 + reg, col(px) = m
    #pragma unroll
    for (int ot = 0; ot < 4; ot++)
        #pragma unroll
        for (int reg = 0; reg < 4; reg++) {
            const int o = ot * 16 + quad * 4 + reg;
            const float sc = g_scale[o], sh = g_shift[o];
            float* ob = out + ((size_t)(b * 64 + o)) * HW + px0;
            #pragma unroll
            for (int pt = 0; pt < 4; pt++) {
                const int pxl = wave * 64 + pt * 16 + m;
                ob[pxl] = fmaxf(0.f, acc[ot][pt][reg] * sc + sh);
            }
        }
}

extern "C" void kernel_launch(void* const* d_in, const int* in_sizes, int n_in,
                              void* d_out, int out_size, void* d_ws, size_t ws_size,
                              hipStream_t stream)
{
    const float* x   = (const float*)d_in[0];
    const float* we  = (const float*)d_in[1];
    const float* wd  = (const float*)d_in[2];
    const float* bng = (const float*)d_in[3];
    const float* bnb = (const float*)d_in[4];
    const float* bnm = (const float*)d_in[5];
    const float* bnv = (const float*)d_in[6];
    const float* cw  = (const float*)d_in[7];
    const float* fg  = (const float*)d_in[8];
    const float* fb  = (const float*)d_in[9];
    const float* fm  = (const float*)d_in[10];
    const float* fv  = (const float*)d_in[11];
    float* out = (float*)d_out;
    _Float16* cat = (_Float16*)d_ws;  // 4*256*65536*2 B = 128 MiB

    prep<<<64, 256, 0, stream>>>(cw, fg, fb, fm, fv, we, wd, bng, bnb, bnm, bnv);
    morph_all<<<dim3(16, 64, 4), 256, 0, stream>>>(x, cat);
    conv_mfma<<<dim3(256, 4), 256, 0, stream>>>(cat, out);
}

// Round 7
// 247.865 us; speedup vs baseline: 13.9643x; 1.0034x over previous
//
#include <hip/hip_runtime.h>
#include <hip/hip_fp16.h>
#include <math.h>

// MSMOM: multi-scale soft morphological opening + BN/ReLU + 1x1 conv + BN/ReLU
// B=4, C=64, H=W=256, k=3, dilations 1..4, beta=15.
//
// Morph computed in exp2-domain: soft-ero/dil are linear correlations on
// P = 2^{-K x} (K = beta*log2e).  S1 = sum W*P  ->  2^{K e} = 1/S1 (rcp);
// dilation: out = C1*log2( sum Wd * (1/S1) ).  No per-pixel max needed:
// 2^{-Kx} spans 2^+-119 (x ~ N(0,1)) and 2^{Ke} spans ~2^[-108,43], both
// within fp32.  Flush-to-zero corner cases land on relu-0-correct outputs.
//
// History notes (keep):
//  - pk-FMA in morph RETIRED (r5: VGPR 68->172, 30x regression).
//  - conv "memory" clobber on the write->read fence RETIRED (r6 vs r5:
//    ~110 us vs ~20 us conv; the clobber re-serializes the unrolled loop's
//    memory pipeline).  Ordering safety now via sched_barrier(0) BEFORE
//    the lgkmcnt fence (compile-time only, no codegen cost).

constexpr int C_ = 64, H_ = 256, W_ = 256;
constexpr int HW = H_ * W_;
constexpr float EPSV = 1e-5f;
constexpr float KL2E = 21.64042561333445f;    // beta * log2(e)
constexpr float C1   = 0.046209812037329684f; // ln(2) / beta

typedef __attribute__((ext_vector_type(8))) _Float16 half8v;
typedef __attribute__((ext_vector_type(4))) _Float16 half4v;
typedef __attribute__((ext_vector_type(4))) float f32x4;
typedef __attribute__((ext_vector_type(2))) float f32x2;

__device__ _Float16 g_wh[64 * 256];  // conv weights fp16, row-major [o][c]
__device__ float g_scale[64];
__device__ float g_shift[64];
__device__ float g_we9e[4 * 64 * 9]; // 2^{K*we}  (morph erosion weights, exp2-domain)
__device__ float g_wd9e[4 * 64 * 9]; // 2^{K*wd}  (morph dilation weights, exp2-domain)
__device__ float g_cs[4 * 64];       // C1 * bn_scale  (per d,c)
__device__ float g_sh[4 * 64];       // bn shift       (per d,c)

__global__ __launch_bounds__(256) void prep(
    const float* __restrict__ cw, const float* __restrict__ g,
    const float* __restrict__ bb, const float* __restrict__ bm,
    const float* __restrict__ bv, const float* __restrict__ we,
    const float* __restrict__ wd, const float* __restrict__ bng,
    const float* __restrict__ bnb, const float* __restrict__ bnm,
    const float* __restrict__ bnv)
{
    int i = blockIdx.x * 256 + threadIdx.x;  // 16384 total
    g_wh[i] = (_Float16)cw[i];
    if (i < 64) {
        float s = g[i] * rsqrtf(bv[i] + EPSV);
        g_scale[i] = s;
        g_shift[i] = bb[i] - bm[i] * s;
    }
    if (i < 2304) {  // 4*64*9 morph weights, exp2-domain (hoisted out of morph_all)
        g_we9e[i] = __builtin_amdgcn_exp2f(KL2E * we[i]);
        g_wd9e[i] = __builtin_amdgcn_exp2f(KL2E * wd[i]);
    }
    if (i < 256) {   // per-(d,c) BN constants
        float s = bng[i] * rsqrtf(bnv[i] + EPSV);
        g_cs[i] = C1 * s;
        g_sh[i] = bnb[i] - bnm[i] * s;
    }
}

// One block = one 64x64 tile of one (b,c); all 4 dilations reuse staged P.
// xs: P = 2^{-K x}, 80 rows x 80 cols, stride 92 (28 mod 32 -> row bank
// offsets cycle uniformly over all 8 cosets).  es: 2^{K e}, 72 rows x 72
// cols, stride 76 (12 mod 32 -> also all 8 cosets; dilation never reads
// cols >71, and the erosion's last col-group writes only cols 64..71).
// PROVEN round-1 body (113 us, VGPR 68) — do not touch the FMA form.
__global__ __launch_bounds__(256) void morph_all(
    const float* __restrict__ x, _Float16* __restrict__ cat)
{
    __shared__ __align__(16) float xs[80 * 92];
    __shared__ __align__(16) float es[72 * 76];
    const int tid = threadIdx.x;
    const int tileW = blockIdx.x & 3, tileH = blockIdx.x >> 2;  // 4x4 tiles
    const int c = blockIdx.y, b = blockIdx.z;
    const int h0 = tileH * 64, w0 = tileW * 64;
    const float* xc = x + (b * C_ + c) * HW;

    // staging: P = 2^{-K x}; out-of-image -> 0 (== 2^{-K*BIG} exactly).
    // 80 rows x 20 float4-groups; group col-validity is all-or-nothing.
    for (int u = tid; u < 1600; u += 256) {
        int r = u / 20, q4 = (u - r * 20) * 4;
        int gh = h0 - 8 + r, gw = w0 - 8 + q4;
        int ch = min(max(gh, 0), 255), cwi = min(max(gw, 0), 252);
        const float4 v = *(const float4*)&xc[ch * W_ + cwi];
        bool ok = ((unsigned)gh < 256u) && ((unsigned)gw < 253u);
        float4 sv;
        sv.x = ok ? __builtin_amdgcn_exp2f(-KL2E * v.x) : 0.f;
        sv.y = ok ? __builtin_amdgcn_exp2f(-KL2E * v.y) : 0.f;
        sv.z = ok ? __builtin_amdgcn_exp2f(-KL2E * v.z) : 0.f;
        sv.w = ok ? __builtin_amdgcn_exp2f(-KL2E * v.w) : 0.f;
        *(float4*)&xs[r * 92 + q4] = sv;
    }

    #pragma unroll
    for (int d = 0; d < 4; d++) {
        const int D = d + 1;
        const int bc = d * C_ + c;

        // weights + BN constants: precomputed in prep, wave-uniform loads
        float w9[9], wd9[9];
        #pragma unroll
        for (int i = 0; i < 9; i++) {
            w9[i]  = g_we9e[bc * 9 + i];
            wd9[i] = g_wd9e[bc * 9 + i];
        }
        const float cs = g_cs[bc];
        const float shift = g_sh[bc];

        __syncthreads();  // staging done / previous dilation reads of es done

        // erosion: 5 col-groups x 72 rows, column-major (bank-uniform).
        // es row a <-> image row h0-4+a <-> xs row a+4.
        for (int g = tid; g < 360; g += 256) {
            const int col = g / 72;            // wave-uniform-ish
            const int row = g - col * 72;
            const int qa0 = col * 16;
            float s16[16];
            #pragma unroll
            for (int p = 0; p < 16; p++) s16[p] = 0.f;
            #pragma unroll
            for (int i = 0; i < 3; i++) {
                const f32x4* xr = (const f32x4*)&xs[(row + 4 + (i - 1) * D) * 92 + qa0];
                f32x4 xw[6];
                #pragma unroll
                for (int k = 0; k < 6; k++) xw[k] = xr[k];
                #pragma unroll
                for (int j = 0; j < 3; j++) {
                    const float wv = w9[i * 3 + j];
                    #pragma unroll
                    for (int p = 0; p < 16; p++) {
                        const int wi = (4 - D) + p + j * D;  // compile-time
                        s16[p] = fmaf(wv, xw[wi >> 2][wi & 3], s16[p]);
                    }
                }
            }
            const bool rowok = (unsigned)(h0 + row - 4) < 256u;
            const int gw0 = w0 + qa0 - 4;
            f32x4 ev[4];
            #pragma unroll
            for (int p = 0; p < 16; p++) {
                float gv = __builtin_amdgcn_rcpf(fmaxf(s16[p], 1e-38f));
                bool ok = rowok && ((unsigned)(gw0 + p) < 256u);
                ev[p >> 2][p & 3] = ok ? gv : 0.f;  // pad: 2^{K*(-BIG)} = 0
            }
            f32x4* ep = (f32x4*)&es[row * 76 + qa0];
            ep[0] = ev[0]; ep[1] = ev[1];
            if (qa0 < 64) { ep[2] = ev[2]; ep[3] = ev[3]; }  // cols 72..79 never read
        }

        __syncthreads();  // es ready

        // dilation: 64 rows x 4 col-groups of 16 px, one group per thread
        {
            const int dr = tid >> 2, dq0 = (tid & 3) * 16;
            float s16[16];
            #pragma unroll
            for (int p = 0; p < 16; p++) s16[p] = 0.f;
            #pragma unroll
            for (int i = 0; i < 3; i++) {
                const f32x4* er = (const f32x4*)&es[(dr + 4 + (i - 1) * D) * 76 + dq0];
                f32x4 ew[6];
                #pragma unroll
                for (int k = 0; k < 6; k++) ew[k] = er[k];
                #pragma unroll
                for (int j = 0; j < 3; j++) {
                    const float wv = wd9[i * 3 + j];
                    #pragma unroll
                    for (int p = 0; p < 16; p++) {
                        const int wi = (4 - D) + p + j * D;
                        s16[p] = fmaf(wv, ew[wi >> 2][wi & 3], s16[p]);
                    }
                }
            }
            half8v hv0, hv1;
            #pragma unroll
            for (int p = 0; p < 16; p++) {
                float y = __builtin_amdgcn_logf(fmaxf(s16[p], 1e-38f)) * cs + shift;
                y = fmaxf(0.f, y);
                if (p < 8) hv0[p] = (_Float16)y; else hv1[p - 8] = (_Float16)y;
            }
            _Float16* cp = &cat[((size_t)((b * 4 + d) * C_ + c)) * HW
                                + (h0 + dr) * W_ + (w0 + dq0)];
            *(half8v*)cp = hv0;
            *(half8v*)(cp + 8) = hv1;
        }
    }
}

// Out[64 x 65536] = W[64x256] * Cat[256x65536] per batch via mfma_f32_16x16x32_f16.
//
// BARRIER-FREE wave-private pipeline (r5 form — the fast one): each wave's
// B-fragment tr-reads touch only its own 5120-B region, so each wave stages
// its OWN 64-px strip (all 32 k-rows) -> producer == consumer, no
// __syncthreads, no compiler vmcnt(0) barrier drains.
//
// FENCE FORM MATTERS (r5 vs r6): a ::: "memory" clobber on the write->read
// fence cost ~5x (it orders every memory op in the 8x-unrolled loop against
// the fence, killing cross-iteration pipelining).  Instead: sched_barrier(0)
// BEFORE the plain lgkmcnt(0) pins the ds_writes above it, sched_barrier(0)
// AFTER pins the tr-reads below (rule 18).  Compile-time only.
//
// VMEM FIFO discipline: A-loads (g_wh, L1-resident) are issued BEFORE the
// cat prefetch so the MFMA's implicit wait is vmcnt(4) -- it never drains
// the depth-2 HBM prefetch.
//
// ds_read_b64_tr_b16 (proven r4/r5): lane addr = sub_base + (lane&15)*8;
// the 16-lane group cooperatively reads the 128-B [4 kr][16 m] subtile and
// lane m receives column m (elem j = kr j).  k = quad*8 + h*4 + j.
__global__ __launch_bounds__(256) void conv_mfma(
    const _Float16* __restrict__ cat, float* __restrict__ out)
{
    __shared__ __align__(16) _Float16 T[2][10240];  // 40,960 B
    const int tid = threadIdx.x;
    const int lane = tid & 63, wave = tid >> 6;
    const int m = lane & 15, quad = lane >> 4;
    const int b = blockIdx.y;
    const int px0 = blockIdx.x * 256;
    const _Float16* catb = cat + (size_t)b * 256 * HW + px0;

    // wave-private staging: lane covers k-row cl2 = lane>>1, half-strip s
    const int cl2 = lane >> 1, s = lane & 1;
    const int pxw = wave * 64 + s * 8;               // global px base (+p*16)
    // LDS write offset (halves): wave region + [pt=p][c4][kr][m]
    const int wbase = wave * 2560 + (cl2 >> 2) * 80 + (cl2 & 3) * 16 + s * 8;

    const uint t0a = (uint)(uintptr_t)&T[0][0];      // LDS byte address
    const uint trbase = t0a + wave * 5120 + quad * 320 + m * 8;

    f32x4 acc[4][4];
    #pragma unroll
    for (int ot = 0; ot < 4; ot++)
        #pragma unroll
        for (int pt = 0; pt < 4; pt++)
            acc[ot][pt] = (f32x4){0.f, 0.f, 0.f, 0.f};

    half8v sv[2][4];
    #pragma unroll
    for (int p = 0; p < 4; p++) {
        sv[0][p] = *(const half8v*)&catb[(size_t)cl2 * HW + pxw + p * 16];
        sv[1][p] = *(const half8v*)&catb[(size_t)(32 + cl2) * HW + pxw + p * 16];
    }

    #pragma unroll
    for (int kc = 0; kc < 8; kc++) {
        const int buf = kc & 1;
        const int c0 = kc * 32;
        // stage chunk (loaded 2 iterations ago) into this wave's region
        _Float16* tw = &T[buf][0] + wbase;
        #pragma unroll
        for (int p = 0; p < 4; p++)
            *(half8v*)(tw + p * 640) = sv[buf][p];

        // A fragments first (L1), THEN the HBM prefetch: vmcnt FIFO keeps
        // the prefetch outstanding across the MFMA phase.
        half8v a0 = *(const half8v*)&g_wh[(0  + m) * 256 + c0 + quad * 8];
        half8v a1 = *(const half8v*)&g_wh[(16 + m) * 256 + c0 + quad * 8];
        half8v a2 = *(const half8v*)&g_wh[(32 + m) * 256 + c0 + quad * 8];
        half8v a3 = *(const half8v*)&g_wh[(48 + m) * 256 + c0 + quad * 8];

        if (kc < 6) {  // prefetch for kc+2
            #pragma unroll
            for (int p = 0; p < 4; p++)
                sv[buf][p] = *(const half8v*)&catb[(size_t)(c0 + 64 + cl2) * HW + pxw + p * 16];
        }

        // wave-local fence: ds_writes pinned above (sched_barrier before),
        // tr-reads pinned below (sched_barrier after).  NO "memory" clobber.
        __builtin_amdgcn_sched_barrier(0);
        asm volatile("s_waitcnt lgkmcnt(0)");
        __builtin_amdgcn_sched_barrier(0);

        // B fragments: 2 tr reads per pt, lane addr covers the 128-B subtile
        const uint tb = trbase + buf * 20480;
        f32x2 trd[4][2];
        #pragma unroll
        for (int pt = 0; pt < 4; pt++) {
            asm volatile("ds_read_b64_tr_b16 %0, %1"
                         : "=v"(trd[pt][0]) : "v"(tb + pt * 1280));
            asm volatile("ds_read_b64_tr_b16 %0, %1"
                         : "=v"(trd[pt][1]) : "v"(tb + pt * 1280 + 160));
        }
        asm volatile("s_waitcnt lgkmcnt(0)");
        __builtin_amdgcn_sched_barrier(0);  // rule 18: keep MFMAs below the wait

        #pragma unroll
        for (int pt = 0; pt < 4; pt++) {
            half4v lo = __builtin_bit_cast(half4v, trd[pt][0]);
            half4v hi = __builtin_bit_cast(half4v, trd[pt][1]);
            half8v bf = __builtin_shufflevector(lo, hi, 0, 1, 2, 3, 4, 5, 6, 7);
            acc[0][pt] = __builtin_amdgcn_mfma_f32_16x16x32_f16(a0, bf, acc[0][pt], 0, 0, 0);
            acc[1][pt] = __builtin_amdgcn_mfma_f32_16x16x32_f16(a1, bf, acc[1][pt], 0, 0, 0);
            acc[2][pt] = __builtin_amdgcn_mfma_f32_16x16x32_f16(a2, bf, acc[2][pt], 0, 0, 0);
            acc[3][pt] = __builtin_amdgcn_mfma_f32_16x16x32_f16(a3, bf, acc[3][pt], 0, 0, 0);
        }
    }

    // D layout: row(o) = quad*4 + reg, col(px) = m
    #pragma unroll
    for (int ot = 0; ot < 4; ot++)
        #pragma unroll
        for (int reg = 0; reg < 4; reg++) {
            const int o = ot * 16 + quad * 4 + reg;
            const float sc = g_scale[o], sh = g_shift[o];
            float* ob = out + ((size_t)(b * 64 + o)) * HW + px0;
            #pragma unroll
            for (int pt = 0; pt < 4; pt++) {
                const int pxl = wave * 64 + pt * 16 + m;
                ob[pxl] = fmaxf(0.f, acc[ot][pt][reg] * sc + sh);
            }
        }
}

extern "C" void kernel_launch(void* const* d_in, const int* in_sizes, int n_in,
                              void* d_out, int out_size, void* d_ws, size_t ws_size,
                              hipStream_t stream)
{
    const float* x   = (const float*)d_in[0];
    const float* we  = (const float*)d_in[1];
    const float* wd  = (const float*)d_in[2];
    const float* bng = (const float*)d_in[3];
    const float* bnb = (const float*)d_in[4];
    const float* bnm = (const float*)d_in[5];
    const float* bnv = (const float*)d_in[6];
    const float* cw  = (const float*)d_in[7];
    const float* fg  = (const float*)d_in[8];
    const float* fb  = (const float*)d_in[9];
    const float* fm  = (const float*)d_in[10];
    const float* fv  = (const float*)d_in[11];
    float* out = (float*)d_out;
    _Float16* cat = (_Float16*)d_ws;  // 4*256*65536*2 B = 128 MiB

    prep<<<64, 256, 0, stream>>>(cw, fg, fb, fm, fv, we, wd, bng, bnb, bnm, bnv);
    morph_all<<<dim3(16, 64, 4), 256, 0, stream>>>(x, cat);
    conv_mfma<<<dim3(256, 4), 256, 0, stream>>>(cat, out);
}

// Round 8
// 244.877 us; speedup vs baseline: 14.1347x; 1.0122x over previous
//
#include <hip/hip_runtime.h>
#include <hip/hip_fp16.h>
#include <math.h>

// MSMOM: multi-scale soft morphological opening + BN/ReLU + 1x1 conv + BN/ReLU
// B=4, C=64, H=W=256, k=3, dilations 1..4, beta=15.
//
// Morph computed in exp2-domain: soft-ero/dil are linear correlations on
// P = 2^{-K x} (K = beta*log2e).  S1 = sum W*P  ->  2^{K e} = 1/S1 (rcp);
// dilation: out = C1*log2( sum Wd * (1/S1) ).  No per-pixel max needed.
//
// History notes (keep):
//  - pk-FMA in morph RETIRED (r5: VGPR 68->172, 30x regression).
//  - conv fence-form experiments (r5/r6/r7) all NEUTRAL; r5's "20us conv"
//    was a cross-run clock artifact.  conv was ~110-130us in ALL variants ->
//    latency-bound on in-flight bytes (~128 B/wave prefetch vs ~11 KiB/CU
//    needed).  r8: deep global_load_lds staging (ring-3, counted vmcnt).

constexpr int C_ = 64, H_ = 256, W_ = 256;
constexpr int HW = H_ * W_;
constexpr float EPSV = 1e-5f;
constexpr float KL2E = 21.64042561333445f;    // beta * log2(e)
constexpr float C1   = 0.046209812037329684f; // ln(2) / beta

typedef __attribute__((ext_vector_type(8))) _Float16 half8v;
typedef __attribute__((ext_vector_type(4))) _Float16 half4v;
typedef __attribute__((ext_vector_type(4))) float f32x4;
typedef __attribute__((ext_vector_type(2))) float f32x2;

typedef const __attribute__((address_space(1))) void gvoid;
typedef __attribute__((address_space(3))) void svoid;

__device__ _Float16 g_wh[64 * 256];  // conv weights fp16, row-major [o][c]
__device__ float g_scale[64];
__device__ float g_shift[64];
__device__ float g_we9e[4 * 64 * 9]; // 2^{K*we}
__device__ float g_wd9e[4 * 64 * 9]; // 2^{K*wd}
__device__ float g_cs[4 * 64];       // C1 * bn_scale  (per d,c)
__device__ float g_sh[4 * 64];       // bn shift       (per d,c)

__global__ __launch_bounds__(256) void prep(
    const float* __restrict__ cw, const float* __restrict__ g,
    const float* __restrict__ bb, const float* __restrict__ bm,
    const float* __restrict__ bv, const float* __restrict__ we,
    const float* __restrict__ wd, const float* __restrict__ bng,
    const float* __restrict__ bnb, const float* __restrict__ bnm,
    const float* __restrict__ bnv)
{
    int i = blockIdx.x * 256 + threadIdx.x;  // 16384 total
    g_wh[i] = (_Float16)cw[i];
    if (i < 64) {
        float s = g[i] * rsqrtf(bv[i] + EPSV);
        g_scale[i] = s;
        g_shift[i] = bb[i] - bm[i] * s;
    }
    if (i < 2304) {
        g_we9e[i] = __builtin_amdgcn_exp2f(KL2E * we[i]);
        g_wd9e[i] = __builtin_amdgcn_exp2f(KL2E * wd[i]);
    }
    if (i < 256) {
        float s = bng[i] * rsqrtf(bnv[i] + EPSV);
        g_cs[i] = C1 * s;
        g_sh[i] = bnb[i] - bnm[i] * s;
    }
}

// PROVEN round-1 morph body (113 us, VGPR 68) — do not touch.
__global__ __launch_bounds__(256) void morph_all(
    const float* __restrict__ x, _Float16* __restrict__ cat)
{
    __shared__ __align__(16) float xs[80 * 92];
    __shared__ __align__(16) float es[72 * 76];
    const int tid = threadIdx.x;
    const int tileW = blockIdx.x & 3, tileH = blockIdx.x >> 2;  // 4x4 tiles
    const int c = blockIdx.y, b = blockIdx.z;
    const int h0 = tileH * 64, w0 = tileW * 64;
    const float* xc = x + (b * C_ + c) * HW;

    for (int u = tid; u < 1600; u += 256) {
        int r = u / 20, q4 = (u - r * 20) * 4;
        int gh = h0 - 8 + r, gw = w0 - 8 + q4;
        int ch = min(max(gh, 0), 255), cwi = min(max(gw, 0), 252);
        const float4 v = *(const float4*)&xc[ch * W_ + cwi];
        bool ok = ((unsigned)gh < 256u) && ((unsigned)gw < 253u);
        float4 sv;
        sv.x = ok ? __builtin_amdgcn_exp2f(-KL2E * v.x) : 0.f;
        sv.y = ok ? __builtin_amdgcn_exp2f(-KL2E * v.y) : 0.f;
        sv.z = ok ? __builtin_amdgcn_exp2f(-KL2E * v.z) : 0.f;
        sv.w = ok ? __builtin_amdgcn_exp2f(-KL2E * v.w) : 0.f;
        *(float4*)&xs[r * 92 + q4] = sv;
    }

    #pragma unroll
    for (int d = 0; d < 4; d++) {
        const int D = d + 1;
        const int bc = d * C_ + c;

        float w9[9], wd9[9];
        #pragma unroll
        for (int i = 0; i < 9; i++) {
            w9[i]  = g_we9e[bc * 9 + i];
            wd9[i] = g_wd9e[bc * 9 + i];
        }
        const float cs = g_cs[bc];
        const float shift = g_sh[bc];

        __syncthreads();

        for (int g = tid; g < 360; g += 256) {
            const int col = g / 72;
            const int row = g - col * 72;
            const int qa0 = col * 16;
            float s16[16];
            #pragma unroll
            for (int p = 0; p < 16; p++) s16[p] = 0.f;
            #pragma unroll
            for (int i = 0; i < 3; i++) {
                const f32x4* xr = (const f32x4*)&xs[(row + 4 + (i - 1) * D) * 92 + qa0];
                f32x4 xw[6];
                #pragma unroll
                for (int k = 0; k < 6; k++) xw[k] = xr[k];
                #pragma unroll
                for (int j = 0; j < 3; j++) {
                    const float wv = w9[i * 3 + j];
                    #pragma unroll
                    for (int p = 0; p < 16; p++) {
                        const int wi = (4 - D) + p + j * D;
                        s16[p] = fmaf(wv, xw[wi >> 2][wi & 3], s16[p]);
                    }
                }
            }
            const bool rowok = (unsigned)(h0 + row - 4) < 256u;
            const int gw0 = w0 + qa0 - 4;
            f32x4 ev[4];
            #pragma unroll
            for (int p = 0; p < 16; p++) {
                float gv = __builtin_amdgcn_rcpf(fmaxf(s16[p], 1e-38f));
                bool ok = rowok && ((unsigned)(gw0 + p) < 256u);
                ev[p >> 2][p & 3] = ok ? gv : 0.f;
            }
            f32x4* ep = (f32x4*)&es[row * 76 + qa0];
            ep[0] = ev[0]; ep[1] = ev[1];
            if (qa0 < 64) { ep[2] = ev[2]; ep[3] = ev[3]; }
        }

        __syncthreads();

        {
            const int dr = tid >> 2, dq0 = (tid & 3) * 16;
            float s16[16];
            #pragma unroll
            for (int p = 0; p < 16; p++) s16[p] = 0.f;
            #pragma unroll
            for (int i = 0; i < 3; i++) {
                const f32x4* er = (const f32x4*)&es[(dr + 4 + (i - 1) * D) * 76 + dq0];
                f32x4 ew[6];
                #pragma unroll
                for (int k = 0; k < 6; k++) ew[k] = er[k];
                #pragma unroll
                for (int j = 0; j < 3; j++) {
                    const float wv = wd9[i * 3 + j];
                    #pragma unroll
                    for (int p = 0; p < 16; p++) {
                        const int wi = (4 - D) + p + j * D;
                        s16[p] = fmaf(wv, ew[wi >> 2][wi & 3], s16[p]);
                    }
                }
            }
            half8v hv0, hv1;
            #pragma unroll
            for (int p = 0; p < 16; p++) {
                float y = __builtin_amdgcn_logf(fmaxf(s16[p], 1e-38f)) * cs + shift;
                y = fmaxf(0.f, y);
                if (p < 8) hv0[p] = (_Float16)y; else hv1[p - 8] = (_Float16)y;
            }
            _Float16* cp = &cat[((size_t)((b * 4 + d) * C_ + c)) * HW
                                + (h0 + dr) * W_ + (w0 + dq0)];
            *(half8v*)cp = hv0;
            *(half8v*)(cp + 8) = hv1;
        }
    }
}

// Out[64 x 65536] = W[64x256] * Cat[256x65536] per batch, mfma_f32_16x16x32_f16.
//
// r8 structure: DEEP HBM->LDS pipeline via global_load_lds (no VGPR staging,
// no ds_writes, still barrier-free / wave-private).
//   - Each wave stages its 4-KiB slice (32 ch x 64 px) per kc with 4
//     global_load_lds dwordx4 instructions; ring of 3 bufs, depth-3 in
//     flight (12 KiB/wave vs 128 B before -> latency fully covered).
//   - Lane-linear dest (HW writes base+lane*16) chosen so the LDS image is
//     exactly the proven [4 kr][16 m] 128-B subtiles:
//       lane = c4sel*32 + p16*8 + chl*2 + half
//       src  ch = c0 + q*8 + c4sel*4 + chl, px = wave*64 + p16*16 + half*8
//       => subtile(c4 = q*2+c4sel, p16) at offset q*1024 + (c4sel*4+p16)*128.
//     tr-read: addr = wavebuf + quad*1024 + h*512 + pt*128 + m*8, fragment
//     order k = quad*8 + h*4 + j (byte-identical to the proven r4-r7 core).
//   - A-loads (g_wh) share the vmcnt FIFO at depth 2 (issue A(kc+2), S(kc+3)
//     each kc).  FIFO = S0,A0,S1,A1,S2,A2,S3,...  Counted waits per kc:
//     need S(kc),A(kc) = first 8(kc+1) ops; issued-so-far gives
//     vmcnt {12,12,12,12,12,12,8,0}.  Never drains the pipeline mid-loop.
//   - Ring-3 WAR safety: S(kc+3) targets buf kc%3, whose tr-reads completed
//     at the lgkmcnt(0) before this kc's MFMAs (issue comes after).
__global__ __launch_bounds__(256) void conv_mfma(
    const _Float16* __restrict__ cat, float* __restrict__ out)
{
    __shared__ __align__(16) _Float16 T[3][4][2048];  // 49,152 B: [ring][wave][halves]
    const int tid = threadIdx.x;
    const int lane = tid & 63, wave = tid >> 6;
    const int m = lane & 15, quad = lane >> 4;
    const int b = blockIdx.y;
    const int px0 = blockIdx.x * 256;
    const _Float16* catb = cat + (size_t)b * 256 * HW + px0;

    // staging decode (per-lane global src; dest is lane-linear by HW)
    const int c4sel = lane >> 5, p16s = (lane >> 3) & 3;
    const int chl = (lane >> 1) & 3, halfs = lane & 1;
    const int ch_in_q = c4sel * 4 + chl;                 // 0..7
    const int px_s = wave * 64 + p16s * 16 + halfs * 8;  // lane's src px base

    const uint t0a = (uint)(uintptr_t)&T[0][0][0];
    const uint trlane = (uint)(quad * 1024 + m * 8);

    f32x4 acc[4][4];
    #pragma unroll
    for (int ot = 0; ot < 4; ot++)
        #pragma unroll
        for (int pt = 0; pt < 4; pt++)
            acc[ot][pt] = (f32x4){0.f, 0.f, 0.f, 0.f};

    half8v a[3][4];

    auto STAGE = [&](int kcs) {
        #pragma unroll
        for (int q = 0; q < 4; ++q) {
            const _Float16* gp = catb + (size_t)(kcs * 32 + q * 8 + ch_in_q) * HW + px_s;
            __builtin_amdgcn_global_load_lds(
                (gvoid*)gp, (svoid*)&T[kcs % 3][wave][q * 512], 16, 0, 0);
        }
    };
    auto LOADA = [&](int kcs) {
        #pragma unroll
        for (int i = 0; i < 4; ++i)
            a[kcs % 3][i] = *(const half8v*)&g_wh[(i * 16 + m) * 256 + kcs * 32 + quad * 8];
    };

    // prologue (FIFO: S0,A0,S1,A1,S2) — sched_barriers pin issue order
    STAGE(0); __builtin_amdgcn_sched_barrier(0);
    LOADA(0); __builtin_amdgcn_sched_barrier(0);
    STAGE(1); __builtin_amdgcn_sched_barrier(0);
    LOADA(1); __builtin_amdgcn_sched_barrier(0);
    STAGE(2); __builtin_amdgcn_sched_barrier(0);

    #pragma unroll
    for (int kc = 0; kc < 8; ++kc) {
        // counted wait: S(kc)+A(kc) complete, deeper stages stay in flight
        if (kc < 6)       asm volatile("s_waitcnt vmcnt(12)");
        else if (kc == 6) asm volatile("s_waitcnt vmcnt(8)");
        else              asm volatile("s_waitcnt vmcnt(0)");
        __builtin_amdgcn_sched_barrier(0);

        const uint wb = t0a + (uint)(((kc % 3) * 4 + wave) * 4096) + trlane;
        f32x2 trd[4][2];
        #pragma unroll
        for (int pt = 0; pt < 4; ++pt) {
            asm volatile("ds_read_b64_tr_b16 %0, %1"
                         : "=v"(trd[pt][0]) : "v"(wb + pt * 128));
            asm volatile("ds_read_b64_tr_b16 %0, %1"
                         : "=v"(trd[pt][1]) : "v"(wb + 512 + pt * 128));
        }
        asm volatile("s_waitcnt lgkmcnt(0)");
        __builtin_amdgcn_sched_barrier(0);  // rule 18: MFMAs stay below the wait

        #pragma unroll
        for (int pt = 0; pt < 4; ++pt) {
            half4v lo = __builtin_bit_cast(half4v, trd[pt][0]);
            half4v hi = __builtin_bit_cast(half4v, trd[pt][1]);
            half8v bf = __builtin_shufflevector(lo, hi, 0, 1, 2, 3, 4, 5, 6, 7);
            acc[0][pt] = __builtin_amdgcn_mfma_f32_16x16x32_f16(a[kc % 3][0], bf, acc[0][pt], 0, 0, 0);
            acc[1][pt] = __builtin_amdgcn_mfma_f32_16x16x32_f16(a[kc % 3][1], bf, acc[1][pt], 0, 0, 0);
            acc[2][pt] = __builtin_amdgcn_mfma_f32_16x16x32_f16(a[kc % 3][2], bf, acc[2][pt], 0, 0, 0);
            acc[3][pt] = __builtin_amdgcn_mfma_f32_16x16x32_f16(a[kc % 3][3], bf, acc[3][pt], 0, 0, 0);
        }
        __builtin_amdgcn_sched_barrier(0);

        if (kc < 6) { LOADA(kc + 2); }          // A depth 2
        __builtin_amdgcn_sched_barrier(0);
        if (kc < 5) { STAGE(kc + 3); }          // stage depth 3, ring-3
        __builtin_amdgcn_sched_barrier(0);
    }

    // D layout: row(o) = quad*4 + reg, col(px) = m
    #pragma unroll
    for (int ot = 0; ot < 4; ot++)
        #pragma unroll
        for (int reg = 0; reg < 4; reg++) {
            const int o = ot * 16 + quad * 4 + reg;
            const float sc = g_scale[o], sh = g_shift[o];
            float* ob = out + ((size_t)(b * 64 + o)) * HW + px0;
            #pragma unroll
            for (int pt = 0; pt < 4; pt++) {
                const int pxl = wave * 64 + pt * 16 + m;
                ob[pxl] = fmaxf(0.f, acc[ot][pt][reg] * sc + sh);
            }
        }
}

extern "C" void kernel_launch(void* const* d_in, const int* in_sizes, int n_in,
                              void* d_out, int out_size, void* d_ws, size_t ws_size,
                              hipStream_t stream)
{
    const float* x   = (const float*)d_in[0];
    const float* we  = (const float*)d_in[1];
    const float* wd  = (const float*)d_in[2];
    const float* bng = (const float*)d_in[3];
    const float* bnb = (const float*)d_in[4];
    const float* bnm = (const float*)d_in[5];
    const float* bnv = (const float*)d_in[6];
    const float* cw  = (const float*)d_in[7];
    const float* fg  = (const float*)d_in[8];
    const float* fb  = (const float*)d_in[9];
    const float* fm  = (const float*)d_in[10];
    const float* fv  = (const float*)d_in[11];
    float* out = (float*)d_out;
    _Float16* cat = (_Float16*)d_ws;  // 4*256*65536*2 B = 128 MiB

    prep<<<64, 256, 0, stream>>>(cw, fg, fb, fm, fv, we, wd, bng, bnb, bnm, bnv);
    morph_all<<<dim3(16, 64, 4), 256, 0, stream>>>(x, cat);
    conv_mfma<<<dim3(256, 4), 256, 0, stream>>>(cat, out);
}